// Round 1
// baseline (381.849 us; speedup 1.0000x reference)
//
#include <hip/hip_runtime.h>

// NLQR: NB=1024, T=128, NS=12, NC=4, N=16.
// Round 7 = Round 6 + single-wave issue diet:
//  - uniform F^T staging: every lane stages 3 elements (lane l -> FT row n=l>>2,
//    k0=3*(l&3)); 3 loads/body (was 4 incl. the R6 OOB-clamp hack), no exec-mask
//    predication, no clamp needed.
//  - Quu/Qux unpack: 32 multi-use (unfusable) DPP movs replaced by 8 broadcast
//    ds_read_b128 from UxS (same-address across lanes -> conflict-free); Schur
//    chain starts directly on read data.
//  - both Schur reciprocals via __builtin_amdgcn_rcpf (1 inst vs ~10-inst IEEE
//    div sequence, on the critical chain, duplicated across all lanes).
//  - FT buffer parity passed as macro args (tb == 3 mod 4 -> compile-time).
// Design otherwise unchanged from R5/R6:
//   Qt = Q + F^T V F; qt = p + F^T v; kt = -Quu^{-1} qu; K = -Quu^{-1} Qux;
//   Vn = Qxx + Qxu K; vn = qx + Qxu kt; u = cu + kt.
//   quad-distributed LDS + DPP quad broadcasts (single-use, foldable) for the
//   m-step / qt-step; 4-deep global prefetch; zero barriers; 1 wave/block.

#define NBQ 1024
#define TT  128

__device__ __forceinline__ float dotf4(float4 a, float4 b) {
  return a.x*b.x + a.y*b.y + a.z*b.z + a.w*b.w;
}
__device__ __forceinline__ float dpp_qx1(float x) {  // quad_perm [1,0,3,2]
  return __int_as_float(__builtin_amdgcn_mov_dpp(__float_as_int(x), 0xB1, 0xF, 0xF, true));
}
__device__ __forceinline__ float dpp_qx2(float x) {  // quad_perm [2,3,0,1]
  return __int_as_float(__builtin_amdgcn_mov_dpp(__float_as_int(x), 0x4E, 0xF, 0xF, true));
}
template<int Q> __device__ __forceinline__ float4 bcast4(float4 v) {
  // broadcast quad-lane Q's float4 to all lanes of the quad (pure VALU)
  float4 r;
  r.x = __int_as_float(__builtin_amdgcn_mov_dpp(__float_as_int(v.x), Q*0x55, 0xF, 0xF, true));
  r.y = __int_as_float(__builtin_amdgcn_mov_dpp(__float_as_int(v.y), Q*0x55, 0xF, 0xF, true));
  r.z = __int_as_float(__builtin_amdgcn_mov_dpp(__float_as_int(v.z), Q*0x55, 0xF, 0xF, true));
  r.w = __int_as_float(__builtin_amdgcn_mov_dpp(__float_as_int(v.w), Q*0x55, 0xF, 0xF, true));
  return r;
}

#define MKS(K, O, MY)  { float4 mk_ = bcast4<O>(MY);                           \
  qt4_.x += gk_[K]*mk_.x; qt4_.y += gk_[K]*mk_.y;                              \
  qt4_.z += gk_[K]*mk_.z; qt4_.w += gk_[K]*mk_.w; }

// One backward body at time T_. Slot regs QV/PV/CV + F-scalars loaded 4 bodies
// ago; stages F^T for T_-1 from prev slot's F-scalars (loaded 3 bodies ago);
// reloads self slot with T_-4 data. FTC/FTN = compile-time parity buffers.
#define BW_BODY(T_, QV, PV, CV, P0,P1,P2, S0,S1,S2, FTC, FTN)                  \
{                                                                              \
  const int  t_   = (T_);                                                      \
  const long bt_  = b*TT + t_;                                                 \
  const long btL_ = b*TT + ((t_ >= 4) ? (t_ - 4) : 0);                         \
  float4 qN_ = *(const float4*)(Qg + btL_*256 + qoff);                         \
  const float* fpL_ = fBase + btL_*fMul + fOfs;                                \
  float fN0_ = fpL_[0], fN1_ = fpL_[fstr_], fN2_ = fpL_[2*fstr_];              \
  float  pN_ = pg[btL_*16 + j];                                                \
  float  cN_ = cug[btL_*4 + q4];                                               \
  /* stage F^T for t_-1: uniform, 3 consecutive elements per lane */           \
  FTN[wix] = P0; FTN[wix+1] = P1; FTN[wix+2] = P2;                             \
  /* reads: f = F col (l&15) (serves m-step AND qt-step), own V row, own vv */ \
  const float4* fj4_ = (const float4*)(FTC + j*12);                            \
  float4 f0_=fj4_[0], f1_=fj4_[1], f2_=fj4_[2];                                \
  const float4* vrow_ = (const float4*)(Vs + (3*r + dmin)*12);                 \
  float4 mv0_=vrow_[0], mv1_=vrow_[1], mv2_=vrow_[2];                          \
  float4 mw_ = *(const float4*)(vvS + 4*dmin);                                 \
  /* m rows via quad broadcast of V rows (single-use -> DPP folds into fma) */ \
  float m0_, m1_, m2_;                                                         \
  { float4 r0_=bcast4<0>(mv0_), r1_=bcast4<0>(mv1_), r2_=bcast4<0>(mv2_);      \
    m0_ = dotf4(r0_,f0_)+dotf4(r1_,f1_)+dotf4(r2_,f2_); }                      \
  { float4 r0_=bcast4<1>(mv0_), r1_=bcast4<1>(mv1_), r2_=bcast4<1>(mv2_);      \
    m1_ = dotf4(r0_,f0_)+dotf4(r1_,f1_)+dotf4(r2_,f2_); }                      \
  { float4 r0_=bcast4<2>(mv0_), r1_=bcast4<2>(mv1_), r2_=bcast4<2>(mv2_);      \
    m2_ = dotf4(r0_,f0_)+dotf4(r1_,f1_)+dotf4(r2_,f2_); }                      \
  msh[(3*r+0)*16 + j] = m0_;                                                   \
  msh[(3*r+1)*16 + j] = m1_;                                                   \
  msh[(3*r+2)*16 + j] = m2_;                                                   \
  /* qtv via vv quad broadcast (fills msh write->read latency) */              \
  float qtv_;                                                                  \
  { float4 w0_=bcast4<0>(mw_), w1_=bcast4<1>(mw_), w2_=bcast4<2>(mw_);         \
    qtv_ = PV + dotf4(w0_,f0_)+dotf4(w1_,f1_)+dotf4(w2_,f2_); }                \
  /* qt tile: lane (cb, i=l&15) computes Qt[i][4cb..4cb+3] */                  \
  float gk_[12] = {f0_.x,f0_.y,f0_.z,f0_.w, f1_.x,f1_.y,f1_.z,f1_.w,           \
                   f2_.x,f2_.y,f2_.z,f2_.w};                                   \
  float4 mys0_ = *(const float4*)(msh + (3*q4+0)*16 + cb4);                    \
  float4 mys1_ = *(const float4*)(msh + (3*q4+1)*16 + cb4);                    \
  float4 mys2_ = *(const float4*)(msh + (3*q4+2)*16 + cb4);                    \
  float4 qt4_ = QV;                                                            \
  MKS(0,0,mys0_) MKS(1,0,mys1_) MKS(2,0,mys2_)                                 \
  MKS(3,1,mys0_) MKS(4,1,mys1_) MKS(5,1,mys2_)                                 \
  MKS(6,2,mys0_) MKS(7,2,mys1_) MKS(8,2,mys2_)                                 \
  MKS(9,3,mys0_) MKS(10,3,mys1_) MKS(11,3,mys2_)                               \
  /* publish Qux|Quu rows, Qxu, qu */                                          \
  if (j >= 12)           *(float4*)(UxS + (j-12)*16 + cb4) = qt4_;             \
  if (cb == 3 && j < 12) *(float4*)(XuS + j*4) = qt4_;                         \
  if (l >= 12 && l < 16) quS[l-12] = qtv_;                                     \
  /* dependent reads, all in one cluster: Quu rows via broadcast b128 reads   */ \
  /* (replaces 32 multi-use DPP movs), Qux rows per-cb, qu, own Xu row        */ \
  float4 mmA_ = *(const float4*)(UxS + 0*16 + 12);                             \
  float4 mmB_ = *(const float4*)(UxS + 1*16 + 12);                             \
  float4 mmC_ = *(const float4*)(UxS + 2*16 + 12);                             \
  float4 mmD_ = *(const float4*)(UxS + 3*16 + 12);                             \
  float4 ux0_ = *(const float4*)(UxS + 0*16 + cb4);                            \
  float4 ux1_ = *(const float4*)(UxS + 1*16 + cb4);                            \
  float4 ux2_ = *(const float4*)(UxS + 2*16 + cb4);                            \
  float4 ux3_ = *(const float4*)(UxS + 3*16 + cb4);                            \
  float4 quv_   = *(const float4*)quS;                                         \
  float4 xr_    = *(const float4*)(XuS + jc*4);                                \
  float mm_[16] = { mmA_.x, mmA_.y, mmA_.z, mmA_.w,                            \
                    mmB_.x, mmB_.y, mmB_.z, mmB_.w,                            \
                    mmC_.x, mmC_.y, mmC_.z, mmC_.w,                            \
                    mmD_.x, mmD_.y, mmD_.z, mmD_.w };                          \
  /* SPD 2x2-block Schur inverse of Quu (raw v_rcp: ~1 ulp, off-chain div) */  \
  float rdp_ = __builtin_amdgcn_rcpf(mm_[0]*mm_[5] - mm_[1]*mm_[1]);           \
  float pi00_ = mm_[5]*rdp_, pi01_ = -mm_[1]*rdp_, pi11_ = mm_[0]*rdp_;        \
  float w00_ = pi00_*mm_[2] + pi01_*mm_[6];                                    \
  float w01_ = pi00_*mm_[3] + pi01_*mm_[7];                                    \
  float w10_ = pi01_*mm_[2] + pi11_*mm_[6];                                    \
  float w11_ = pi01_*mm_[3] + pi11_*mm_[7];                                    \
  float t00_ = mm_[10] - (mm_[2]*w00_ + mm_[6]*w10_);                          \
  float t01_ = mm_[11] - (mm_[2]*w01_ + mm_[6]*w11_);                          \
  float t11_ = mm_[15] - (mm_[3]*w01_ + mm_[7]*w11_);                          \
  float rdt_ = __builtin_amdgcn_rcpf(t00_*t11_ - t01_*t01_);                   \
  float ti00_ = t11_*rdt_, ti01_ = -t01_*rdt_, ti11_ = t00_*rdt_;              \
  float u00_ = -(w00_*ti00_ + w01_*ti01_);                                     \
  float u01_ = -(w00_*ti01_ + w01_*ti11_);                                     \
  float u10_ = -(w10_*ti00_ + w11_*ti01_);                                     \
  float u11_ = -(w10_*ti01_ + w11_*ti11_);                                     \
  float i00_ = pi00_ - (u00_*w00_ + u01_*w01_);                                \
  float i01_ = pi01_ - (u00_*w10_ + u01_*w11_);                                \
  float i11_ = pi11_ - (u10_*w10_ + u11_*w11_);                                \
  float inv_[16] = { i00_, i01_, u00_, u01_,                                   \
                     i01_, i11_, u10_, u11_,                                   \
                     u00_, u10_, ti00_, ti01_,                                 \
                     u01_, u11_, ti01_, ti11_ };                               \
  float kt0_ = -(inv_[0] *quv_.x + inv_[1] *quv_.y + inv_[2] *quv_.z + inv_[3] *quv_.w); \
  float kt1_ = -(inv_[4] *quv_.x + inv_[5] *quv_.y + inv_[6] *quv_.z + inv_[7] *quv_.w); \
  float kt2_ = -(inv_[8] *quv_.x + inv_[9] *quv_.y + inv_[10]*quv_.z + inv_[11]*quv_.w); \
  float kt3_ = -(inv_[12]*quv_.x + inv_[13]*quv_.y + inv_[14]*quv_.z + inv_[15]*quv_.w); \
  float4 kc_[4];                                                               \
  _Pragma("unroll")                                                            \
  for (int c_ = 0; c_ < 4; ++c_) {                                             \
    kc_[c_].x = -(inv_[c_*4+0]*ux0_.x + inv_[c_*4+1]*ux1_.x + inv_[c_*4+2]*ux2_.x + inv_[c_*4+3]*ux3_.x); \
    kc_[c_].y = -(inv_[c_*4+0]*ux0_.y + inv_[c_*4+1]*ux1_.y + inv_[c_*4+2]*ux2_.y + inv_[c_*4+3]*ux3_.y); \
    kc_[c_].z = -(inv_[c_*4+0]*ux0_.z + inv_[c_*4+1]*ux1_.z + inv_[c_*4+2]*ux2_.z + inv_[c_*4+3]*ux3_.z); \
    kc_[c_].w = -(inv_[c_*4+0]*ux0_.w + inv_[c_*4+1]*ux1_.w + inv_[c_*4+2]*ux2_.w + inv_[c_*4+3]*ux3_.w); \
  }                                                                            \
  if (j < 12) {                                                                \
    float4 vn4_;                                                               \
    vn4_.x = qt4_.x + xr_.x*kc_[0].x + xr_.y*kc_[1].x + xr_.z*kc_[2].x + xr_.w*kc_[3].x; \
    vn4_.y = qt4_.y + xr_.x*kc_[0].y + xr_.y*kc_[1].y + xr_.z*kc_[2].y + xr_.w*kc_[3].y; \
    vn4_.z = qt4_.z + xr_.x*kc_[0].z + xr_.y*kc_[1].z + xr_.z*kc_[2].z + xr_.w*kc_[3].z; \
    vn4_.w = qt4_.w + xr_.x*kc_[0].w + xr_.y*kc_[1].w + xr_.z*kc_[2].w + xr_.w*kc_[3].w; \
    if (cb < 3) *(float4*)(Vs + j*12 + cb4) = vn4_;                            \
  }                                                                            \
  if (l < 12)                                                                  \
    vvS[l] = qtv_ + xr_.x*kt0_ + xr_.y*kt1_ + xr_.z*kt2_ + xr_.w*kt3_;         \
  float uv_ = CV + ((q4==0)?kt0_:(q4==1)?kt1_:(q4==2)?kt2_:kt3_);              \
  if (l < 4) { us_out[bt_*4 + l] = uv_; uL[t_*4 + l] = uv_; }                  \
  QV = qN_; S0 = fN0_; S1 = fN1_; S2 = fN2_; PV = pN_; CV = cN_;               \
}

__global__ __launch_bounds__(64, 1) void lqr_fused(
    const float* __restrict__ Qg, const float* __restrict__ pg,
    const float* __restrict__ Ag, const float* __restrict__ Bg,
    const float* __restrict__ cug, const float* __restrict__ xinit,
    float* __restrict__ out)
{
  __shared__ __align__(16) float lds[1376];
  float* FT0 = lds;        // [16][12] F^T buffer 0  (FT[n][k] = F[k][n])
  float* FT1 = lds + 192;  // [16][12] F^T buffer 1
  float* Vs  = lds + 384;  // [12][12]
  float* vvS = lds + 528;  // [12]
  float* msh = lds + 544;  // [12][16]
  float* UxS = lds + 736;  // [4][16]
  float* XuS = lds + 800;  // [12][4]
  float* quS = lds + 848;  // [4]
  float* uL  = lds + 864;  // [128][4]

  const int l    = threadIdx.x;
  const int j    = l & 15;         // m-step col / qt-step row i (f==g trick)
  const int r    = l >> 4;         // m-step row group
  const int q4   = l & 3;
  const int cb   = l >> 4;         // qt-step column block
  const int cb4  = cb << 2;
  const int dmin = (q4 < 2) ? q4 : 2;
  const int jc   = (j < 12) ? j : 11;
  const long b   = blockIdx.x;

  // uniform F^T staging map: lane l stages FT[n][k0..k0+2] (3l..3l+2 of 192,
  // never crosses a row since 3l mod 12 ∈ {0,3,6,9})
  const int  n_   = l >> 2;
  const int  k0_  = 3*(l & 3);
  const int  wix  = n_*12 + k0_;
  const bool isA  = (n_ < 12);
  const float* fBase = isA ? Ag : Bg;
  const int  fMul  = isA ? 144 : 48;     // floats per (b,t) in A / B
  const int  fstr_ = isA ? 12  : 4;      // row stride (floats)
  const int  fOfs  = isA ? (k0_*12 + n_) : (k0_*4 + (n_ - 12));
  const int  qoff  = j * 16 + cb4;       // Q[i][4cb..]

  float* xs_out = out;
  float* us_out = out + (long)NBQ*TT*12;
  float* c_out  = out + (long)NBQ*TT*12 + (long)NBQ*TT*4;

  if (j < 12 && cb < 3) *(float4*)(Vs + j*12 + cb4) = make_float4(0.f,0.f,0.f,0.f);
  if (l < 12) vvS[l] = 0.f;

  // ---- prologue: 4 slots (t = 127..124), stage FT(127) into buf1 ----
  const long base = b*TT;
  float4 q3v,q2v,q1v,q0v;
  float  p3v,c3v,p2v,c2v,p1v,c1v,p0v,c0v;
  float  f3a,f3b,f3c, f2a,f2b,f2c, f1a,f1b,f1c, f0a,f0b,f0c;
  {
    long bt;
    bt = base+127; q3v=*(const float4*)(Qg+bt*256+qoff); p3v=pg[bt*16+j]; c3v=cug[bt*4+q4];
    { const float* fp = fBase + bt*fMul + fOfs; f3a=fp[0]; f3b=fp[fstr_]; f3c=fp[2*fstr_]; }
    bt = base+126; q2v=*(const float4*)(Qg+bt*256+qoff); p2v=pg[bt*16+j]; c2v=cug[bt*4+q4];
    { const float* fp = fBase + bt*fMul + fOfs; f2a=fp[0]; f2b=fp[fstr_]; f2c=fp[2*fstr_]; }
    bt = base+125; q1v=*(const float4*)(Qg+bt*256+qoff); p1v=pg[bt*16+j]; c1v=cug[bt*4+q4];
    { const float* fp = fBase + bt*fMul + fOfs; f1a=fp[0]; f1b=fp[fstr_]; f1c=fp[2*fstr_]; }
    bt = base+124; q0v=*(const float4*)(Qg+bt*256+qoff); p0v=pg[bt*16+j]; c0v=cug[bt*4+q4];
    { const float* fp = fBase + bt*fMul + fOfs; f0a=fp[0]; f0b=fp[fstr_]; f0c=fp[2*fstr_]; }
  }
  FT1[wix] = f3a; FT1[wix+1] = f3b; FT1[wix+2] = f3c;

  // ---- backward scan, unrolled x4 with slot rotation ----
  // tb ≡ 3 (mod 4): FT parity per position is compile-time (FT1,FT0,FT1,FT0)
  #pragma unroll 1
  for (int tb = TT-1; tb >= 3; tb -= 4) {
    BW_BODY(tb,   q3v, p3v, c3v,  f2a,f2b,f2c,  f3a,f3b,f3c, FT1, FT0)
    BW_BODY(tb-1, q2v, p2v, c2v,  f1a,f1b,f1c,  f2a,f2b,f2c, FT0, FT1)
    BW_BODY(tb-2, q1v, p1v, c1v,  f0a,f0b,f0c,  f1a,f1b,f1c, FT1, FT0)
    BW_BODY(tb-3, q0v, p0v, c0v,  f3a,f3b,f3c,  f0a,f0b,f0c, FT0, FT1)
  }

  // ---------------- forward rollout + cost ----------------
  const int i4  = l >> 2;
  const int c0f = q4 << 2;
  const int i4c = (i4 < 12) ? i4 : 11;
  const int sl0 = (c0f+0)<<2, sl1 = (c0f+1)<<2, sl2 = (c0f+2)<<2, sl3 = (c0f+3)<<2;
  float s = xinit[b*12 + i4c];
  float cacc = 0.f;

  const long bt0 = base;
  float4 qfA = *(const float4*)(Qg + bt0*256 + 4*l);
  float4 ffA = (q4 < 3) ? *(const float4*)(Ag + bt0*144 + i4c*12 + c0f)
                        : *(const float4*)(Bg + bt0*48  + i4c*4);
  float  pfA = pg[bt0*16 + i4];
  float4 qfB = *(const float4*)(Qg + (bt0+1)*256 + 4*l);
  float4 ffB = (q4 < 3) ? *(const float4*)(Ag + (bt0+1)*144 + i4c*12 + c0f)
                        : *(const float4*)(Bg + (bt0+1)*48  + i4c*4);
  float  pfB = pg[(bt0+1)*16 + i4];
  float4 qfC = *(const float4*)(Qg + (bt0+2)*256 + 4*l);
  float4 ffC = (q4 < 3) ? *(const float4*)(Ag + (bt0+2)*144 + i4c*12 + c0f)
                        : *(const float4*)(Bg + (bt0+2)*48  + i4c*4);
  float  pfC = pg[(bt0+2)*16 + i4];

  #pragma unroll 1
  for (int t = 0; t < TT; ++t) {
    const long btp = bt0 + ((t+3 < TT-1) ? t+3 : TT-1);
    float4 qfD = *(const float4*)(Qg + btp*256 + 4*l);
    float4 ffD = (q4 < 3) ? *(const float4*)(Ag + btp*144 + i4c*12 + c0f)
                          : *(const float4*)(Bg + btp*48  + i4c*4);
    float  pfD = pg[btp*16 + i4];

    float4 u4 = *(const float4*)(uL + t*4);

    float4 xg;
    xg.x = __shfl(s, sl0, 64); xg.y = __shfl(s, sl1, 64);
    xg.z = __shfl(s, sl2, 64); xg.w = __shfl(s, sl3, 64);
    float4 xuq = (q4 < 3) ? xg : u4;
    float xui = (i4 < 12) ? s
              : (i4 == 12) ? u4.x : (i4 == 13) ? u4.y : (i4 == 14) ? u4.z : u4.w;

    if (q4 == 0 && i4 < 12) xs_out[(bt0+t)*12 + i4] = s;

    cacc += 0.5f * xui * dotf4(qfA, xuq);
    if (q4 == 0) cacc += xui * pfA;

    float zx = dotf4(ffA, xuq);
    zx += dpp_qx1(zx);
    zx += dpp_qx2(zx);
    s = zx;

    qfA = qfB; ffA = ffB; pfA = pfB;
    qfB = qfC; ffB = ffC; pfB = pfC;
    qfC = qfD; ffC = ffD; pfC = pfD;
  }

  cacc += __shfl_xor(cacc, 32, 64);
  cacc += __shfl_xor(cacc, 16, 64);
  cacc += __shfl_xor(cacc, 8, 64);
  cacc += __shfl_xor(cacc, 4, 64);
  cacc += dpp_qx2(cacc);
  cacc += dpp_qx1(cacc);
  if (l == 0) c_out[b] = cacc;
}

extern "C" void kernel_launch(void* const* d_in, const int* in_sizes, int n_in,
                              void* d_out, int out_size, void* d_ws, size_t ws_size,
                              hipStream_t stream) {
  const float* xinit = (const float*)d_in[0];
  // d_in[1] = current_x (unused by reference), d_in[7] = time (unused)
  const float* cu = (const float*)d_in[2];
  const float* Q  = (const float*)d_in[3];
  const float* p  = (const float*)d_in[4];
  const float* A  = (const float*)d_in[5];
  const float* Bm = (const float*)d_in[6];
  float* out = (float*)d_out;

  lqr_fused<<<dim3(NBQ), dim3(64), 0, stream>>>(Q, p, A, Bm, cu, xinit, out);
}

// Round 3
// 371.228 us; speedup vs baseline: 1.0286x; 1.0286x over previous
//
#include <hip/hip_runtime.h>

// NLQR: NB=1024, T=128, NS=12, NC=4, N=16.
// Round 8 (resubmit — R2 bench was GPUAcquisitionTimeout, kernel never ran)
// = Round 7 + SINGLE-BASIC-BLOCK backward body (de-predication):
//  - all conditional stores -> unconditional stores with per-lane address
//    select (cndmask, no exec-mask regions, no s_cbranch_execz BB splits).
//  - staging arrays UxS/XuS/quS/Vs/vvS replaced by all-lane publish buffers:
//    stg4[swz(l)] <- qt4_ (b128, contiguous, XOR-swizzled so Qux-row broadcast
//    reads hit distinct bank quads), qtS[l] <- qtv_, vns[l] <- vn4_,
//    vvF[l] <- vv. Readers remap to publishing lane's slot (same values).
//  - per-body GLOBAL us_out store removed; uL flushed coalesced post-loop.
//  - forward xs_out per-iter store -> xsL in LDS + coalesced flush; cacc
//    predicate -> 0/1 mask multiply. Forward body is 1 BB too.
//  - qu published immediately after qtv_ (round trip hides under MKS).
// Rationale: R7 showed stall-dominated (VALU 42->36.5%, time -1.5%): BB
// fragmentation from ~6 exec-mask regions/body blocks the scheduler from
// hoisting loads/staging into the Schur + LDS-round-trip bubbles.
// Math per real lane is bit-identical to R7.

#define NBQ 1024
#define TT  128

// publish-slot swizzle: distinct bank quads for the 4 Qux-row broadcast reads
#define SSLOT(x) ((x) ^ ((((x) >> 4) << 1)))

__device__ __forceinline__ float dotf4(float4 a, float4 b) {
  return a.x*b.x + a.y*b.y + a.z*b.z + a.w*b.w;
}
__device__ __forceinline__ float dpp_qx1(float x) {  // quad_perm [1,0,3,2]
  return __int_as_float(__builtin_amdgcn_mov_dpp(__float_as_int(x), 0xB1, 0xF, 0xF, true));
}
__device__ __forceinline__ float dpp_qx2(float x) {  // quad_perm [2,3,0,1]
  return __int_as_float(__builtin_amdgcn_mov_dpp(__float_as_int(x), 0x4E, 0xF, 0xF, true));
}
template<int Q> __device__ __forceinline__ float4 bcast4(float4 v) {
  // broadcast quad-lane Q's float4 to all lanes of the quad (pure VALU)
  float4 r;
  r.x = __int_as_float(__builtin_amdgcn_mov_dpp(__float_as_int(v.x), Q*0x55, 0xF, 0xF, true));
  r.y = __int_as_float(__builtin_amdgcn_mov_dpp(__float_as_int(v.y), Q*0x55, 0xF, 0xF, true));
  r.z = __int_as_float(__builtin_amdgcn_mov_dpp(__float_as_int(v.z), Q*0x55, 0xF, 0xF, true));
  r.w = __int_as_float(__builtin_amdgcn_mov_dpp(__float_as_int(v.w), Q*0x55, 0xF, 0xF, true));
  return r;
}

#define MKS(K, O, MY)  { float4 mk_ = bcast4<O>(MY);                           \
  qt4_.x += gk_[K]*mk_.x; qt4_.y += gk_[K]*mk_.y;                              \
  qt4_.z += gk_[K]*mk_.z; qt4_.w += gk_[K]*mk_.w; }

// One backward body at time T_. Slot regs QV/PV/CV + F-scalars loaded 4 bodies
// ago; stages F^T for T_-1 from prev slot's F-scalars; reloads self slot with
// T_-4 data. FTC/FTN = compile-time parity buffers. ZERO exec-mask regions.
#define BW_BODY(T_, QV, PV, CV, P0,P1,P2, S0,S1,S2, FTC, FTN)                  \
{                                                                              \
  const int  t_   = (T_);                                                      \
  const long btL_ = b*TT + ((t_ >= 4) ? (t_ - 4) : 0);                         \
  float4 qN_ = *(const float4*)(Qg + btL_*256 + qoff);                         \
  const float* fpL_ = fBase + btL_*fMul + fOfs;                                \
  float fN0_ = fpL_[0], fN1_ = fpL_[fstr_], fN2_ = fpL_[2*fstr_];              \
  float  pN_ = pg[btL_*16 + j];                                                \
  float  cN_ = cug[btL_*4 + q4];                                               \
  /* stage F^T for t_-1: uniform, 3 consecutive elements per lane */           \
  FTN[wix] = P0; FTN[wix+1] = P1; FTN[wix+2] = P2;                             \
  /* reads: f = F col (l&15), own V row piece from publish slots, vv */        \
  const float4* fj4_ = (const float4*)(FTC + j*12);                            \
  float4 f0_=fj4_[0], f1_=fj4_[1], f2_=fj4_[2];                                \
  float4 mv0_ = vns4[kR], mv1_ = vns4[16+kR], mv2_ = vns4[32+kR];              \
  float4 mw_ = *(const float4*)(vvF + 4*dmin);                                 \
  /* m rows via quad broadcast of V rows (single-use -> DPP folds into fma) */ \
  float m0_, m1_, m2_;                                                         \
  { float4 r0_=bcast4<0>(mv0_), r1_=bcast4<0>(mv1_), r2_=bcast4<0>(mv2_);      \
    m0_ = dotf4(r0_,f0_)+dotf4(r1_,f1_)+dotf4(r2_,f2_); }                      \
  { float4 r0_=bcast4<1>(mv0_), r1_=bcast4<1>(mv1_), r2_=bcast4<1>(mv2_);      \
    m1_ = dotf4(r0_,f0_)+dotf4(r1_,f1_)+dotf4(r2_,f2_); }                      \
  { float4 r0_=bcast4<2>(mv0_), r1_=bcast4<2>(mv1_), r2_=bcast4<2>(mv2_);      \
    m2_ = dotf4(r0_,f0_)+dotf4(r1_,f1_)+dotf4(r2_,f2_); }                      \
  msh[(3*r+0)*16 + j] = m0_;                                                   \
  msh[(3*r+1)*16 + j] = m1_;                                                   \
  msh[(3*r+2)*16 + j] = m2_;                                                   \
  /* qtv via vv quad broadcast; publish qu slice immediately (hides under MKS) */ \
  float qtv_;                                                                  \
  { float4 w0_=bcast4<0>(mw_), w1_=bcast4<1>(mw_), w2_=bcast4<2>(mw_);         \
    qtv_ = PV + dotf4(w0_,f0_)+dotf4(w1_,f1_)+dotf4(w2_,f2_); }                \
  qtS[l] = qtv_;                                                               \
  /* qt tile: lane (cb, i=l&15) computes Qt[i][4cb..4cb+3] */                  \
  float gk_[12] = {f0_.x,f0_.y,f0_.z,f0_.w, f1_.x,f1_.y,f1_.z,f1_.w,           \
                   f2_.x,f2_.y,f2_.z,f2_.w};                                   \
  float4 mys0_ = *(const float4*)(msh + (3*q4+0)*16 + cb4);                    \
  float4 mys1_ = *(const float4*)(msh + (3*q4+1)*16 + cb4);                    \
  float4 mys2_ = *(const float4*)(msh + (3*q4+2)*16 + cb4);                    \
  float4 qt4_ = QV;                                                            \
  MKS(0,0,mys0_) MKS(1,0,mys1_) MKS(2,0,mys2_)                                 \
  MKS(3,1,mys0_) MKS(4,1,mys1_) MKS(5,1,mys2_)                                 \
  MKS(6,2,mys0_) MKS(7,2,mys1_) MKS(8,2,mys2_)                                 \
  MKS(9,3,mys0_) MKS(10,3,mys1_) MKS(11,3,mys2_)                               \
  /* publish qt4_ of ALL lanes (contiguous b128, swizzled slots) */            \
  stg4[sw_] = qt4_;                                                            \
  /* dependent read cluster: Quu rows (broadcast), Qux rows, qu, own Xu row */ \
  float4 mmA_ = stg4[SSLOT(60)];                                               \
  float4 mmB_ = stg4[SSLOT(61)];                                               \
  float4 mmC_ = stg4[SSLOT(62)];                                               \
  float4 mmD_ = stg4[SSLOT(63)];                                               \
  float4 ux0_ = stg4[sux0], ux1_ = stg4[sux1], ux2_ = stg4[sux2], ux3_ = stg4[sux3]; \
  float4 quv_ = *(const float4*)(qtS + 12);                                    \
  float4 xr_  = stg4[sxr];                                                     \
  float mm_[16] = { mmA_.x, mmA_.y, mmA_.z, mmA_.w,                            \
                    mmB_.x, mmB_.y, mmB_.z, mmB_.w,                            \
                    mmC_.x, mmC_.y, mmC_.z, mmC_.w,                            \
                    mmD_.x, mmD_.y, mmD_.z, mmD_.w };                          \
  /* SPD 2x2-block Schur inverse of Quu (raw v_rcp) */                         \
  float rdp_ = __builtin_amdgcn_rcpf(mm_[0]*mm_[5] - mm_[1]*mm_[1]);           \
  float pi00_ = mm_[5]*rdp_, pi01_ = -mm_[1]*rdp_, pi11_ = mm_[0]*rdp_;        \
  float w00_ = pi00_*mm_[2] + pi01_*mm_[6];                                    \
  float w01_ = pi00_*mm_[3] + pi01_*mm_[7];                                    \
  float w10_ = pi01_*mm_[2] + pi11_*mm_[6];                                    \
  float w11_ = pi01_*mm_[3] + pi11_*mm_[7];                                    \
  float t00_ = mm_[10] - (mm_[2]*w00_ + mm_[6]*w10_);                          \
  float t01_ = mm_[11] - (mm_[2]*w01_ + mm_[6]*w11_);                          \
  float t11_ = mm_[15] - (mm_[3]*w01_ + mm_[7]*w11_);                          \
  float rdt_ = __builtin_amdgcn_rcpf(t00_*t11_ - t01_*t01_);                   \
  float ti00_ = t11_*rdt_, ti01_ = -t01_*rdt_, ti11_ = t00_*rdt_;              \
  float u00_ = -(w00_*ti00_ + w01_*ti01_);                                     \
  float u01_ = -(w00_*ti01_ + w01_*ti11_);                                     \
  float u10_ = -(w10_*ti00_ + w11_*ti01_);                                     \
  float u11_ = -(w10_*ti01_ + w11_*ti11_);                                     \
  float i00_ = pi00_ - (u00_*w00_ + u01_*w01_);                                \
  float i01_ = pi01_ - (u00_*w10_ + u01_*w11_);                                \
  float i11_ = pi11_ - (u10_*w10_ + u11_*w11_);                                \
  float inv_[16] = { i00_, i01_, u00_, u01_,                                   \
                     i01_, i11_, u10_, u11_,                                   \
                     u00_, u10_, ti00_, ti01_,                                 \
                     u01_, u11_, ti01_, ti11_ };                               \
  float kt0_ = -(inv_[0] *quv_.x + inv_[1] *quv_.y + inv_[2] *quv_.z + inv_[3] *quv_.w); \
  float kt1_ = -(inv_[4] *quv_.x + inv_[5] *quv_.y + inv_[6] *quv_.z + inv_[7] *quv_.w); \
  float kt2_ = -(inv_[8] *quv_.x + inv_[9] *quv_.y + inv_[10]*quv_.z + inv_[11]*quv_.w); \
  float kt3_ = -(inv_[12]*quv_.x + inv_[13]*quv_.y + inv_[14]*quv_.z + inv_[15]*quv_.w); \
  float4 kc_[4];                                                               \
  _Pragma("unroll")                                                            \
  for (int c_ = 0; c_ < 4; ++c_) {                                             \
    kc_[c_].x = -(inv_[c_*4+0]*ux0_.x + inv_[c_*4+1]*ux1_.x + inv_[c_*4+2]*ux2_.x + inv_[c_*4+3]*ux3_.x); \
    kc_[c_].y = -(inv_[c_*4+0]*ux0_.y + inv_[c_*4+1]*ux1_.y + inv_[c_*4+2]*ux2_.y + inv_[c_*4+3]*ux3_.y); \
    kc_[c_].z = -(inv_[c_*4+0]*ux0_.z + inv_[c_*4+1]*ux1_.z + inv_[c_*4+2]*ux2_.z + inv_[c_*4+3]*ux3_.z); \
    kc_[c_].w = -(inv_[c_*4+0]*ux0_.w + inv_[c_*4+1]*ux1_.w + inv_[c_*4+2]*ux2_.w + inv_[c_*4+3]*ux3_.w); \
  }                                                                            \
  /* all-lane vn publish (garbage slots never read) */                         \
  float4 vn4_;                                                                 \
  vn4_.x = qt4_.x + xr_.x*kc_[0].x + xr_.y*kc_[1].x + xr_.z*kc_[2].x + xr_.w*kc_[3].x; \
  vn4_.y = qt4_.y + xr_.x*kc_[0].y + xr_.y*kc_[1].y + xr_.z*kc_[2].y + xr_.w*kc_[3].y; \
  vn4_.z = qt4_.z + xr_.x*kc_[0].z + xr_.y*kc_[1].z + xr_.z*kc_[2].z + xr_.w*kc_[3].z; \
  vn4_.w = qt4_.w + xr_.x*kc_[0].w + xr_.y*kc_[1].w + xr_.z*kc_[2].w + xr_.w*kc_[3].w; \
  vns4[l] = vn4_;                                                              \
  vvF[l] = qtv_ + xr_.x*kt0_ + xr_.y*kt1_ + xr_.z*kt2_ + xr_.w*kt3_;           \
  float uv_ = CV + ((q4==0)?kt0_:(q4==1)?kt1_:(q4==2)?kt2_:kt3_);              \
  upt[0] = uv_; upt -= ustp;                                                   \
  QV = qN_; S0 = fN0_; S1 = fN1_; S2 = fN2_; PV = pN_; CV = cN_;               \
}

__global__ __launch_bounds__(64, 1) void lqr_fused(
    const float* __restrict__ Qg, const float* __restrict__ pg,
    const float* __restrict__ Ag, const float* __restrict__ Bg,
    const float* __restrict__ cug, const float* __restrict__ xinit,
    float* __restrict__ out)
{
  __shared__ __align__(16) float lds[3328];
  float*  FT0  = lds;                    // [16][12] F^T buffer 0
  float*  FT1  = lds + 192;              // [16][12] F^T buffer 1
  float*  msh  = lds + 384;              // [12][16]
  float4* stg4 = (float4*)(lds + 576);   // [64] qt4_ publish (swizzled slots)
  float4* vns4 = (float4*)(lds + 832);   // [64] vn4_ publish
  float*  qtS  = lds + 1088;             // [64] qtv_ publish
  float*  vvF  = lds + 1152;             // [64] vv publish
  float*  uL   = lds + 1216;             // [128][4]
  float*  dmpS = lds + 1728;             // [64] dump row (never read)
  float*  xsL  = lds + 1792;             // [128][12]

  const int l    = threadIdx.x;
  const int j    = l & 15;         // m-step col / qt-step row i
  const int r    = l >> 4;         // m-step row group
  const int q4   = l & 3;
  const int cb   = l >> 4;         // qt-step column block
  const int cb4  = cb << 2;
  const int dmin = (q4 < 2) ? q4 : 2;
  const int jc   = (j < 12) ? j : 11;
  const long b   = blockIdx.x;
  const int  kR  = 3*r + dmin;

  // publish-slot indices (hoisted)
  const int sw_  = SSLOT(l);
  const int sux0 = SSLOT(16*cb + 12), sux1 = SSLOT(16*cb + 13);
  const int sux2 = SSLOT(16*cb + 14), sux3 = SSLOT(16*cb + 15);
  const int sxr  = SSLOT(48 + jc);

  // uniform F^T staging map: lane l stages FT[n][k0..k0+2]
  const int  n_   = l >> 2;
  const int  k0_  = 3*(l & 3);
  const int  wix  = n_*12 + k0_;
  const bool isA  = (n_ < 12);
  const float* fBase = isA ? Ag : Bg;
  const int  fMul  = isA ? 144 : 48;
  const int  fstr_ = isA ? 12  : 4;
  const int  fOfs  = isA ? (k0_*12 + n_) : (k0_*4 + (n_ - 12));
  const int  qoff  = j * 16 + cb4;

  // u store: lanes 0..3 write uL[t*4+l], others to dump (b32, conflict-free)
  float* up0 = (l < 4) ? (uL + l) : (dmpS + l);
  const int ustp = (l < 4) ? 4 : 0;
  float* upt = up0 + 127*ustp;   // walks t = 127..0 via upt -= ustp

  float* xs_out = out;
  float* us_out = out + (long)NBQ*TT*12;
  float* c_out  = out + (long)NBQ*TT*12 + (long)NBQ*TT*4;

  vns4[l] = make_float4(0.f,0.f,0.f,0.f);
  vvF[l]  = 0.f;

  // ---- prologue: 4 slots (t = 127..124), stage FT(127) into buf1 ----
  const long base = b*TT;
  float4 q3v,q2v,q1v,q0v;
  float  p3v,c3v,p2v,c2v,p1v,c1v,p0v,c0v;
  float  f3a,f3b,f3c, f2a,f2b,f2c, f1a,f1b,f1c, f0a,f0b,f0c;
  {
    long bt;
    bt = base+127; q3v=*(const float4*)(Qg+bt*256+qoff); p3v=pg[bt*16+j]; c3v=cug[bt*4+q4];
    { const float* fp = fBase + bt*fMul + fOfs; f3a=fp[0]; f3b=fp[fstr_]; f3c=fp[2*fstr_]; }
    bt = base+126; q2v=*(const float4*)(Qg+bt*256+qoff); p2v=pg[bt*16+j]; c2v=cug[bt*4+q4];
    { const float* fp = fBase + bt*fMul + fOfs; f2a=fp[0]; f2b=fp[fstr_]; f2c=fp[2*fstr_]; }
    bt = base+125; q1v=*(const float4*)(Qg+bt*256+qoff); p1v=pg[bt*16+j]; c1v=cug[bt*4+q4];
    { const float* fp = fBase + bt*fMul + fOfs; f1a=fp[0]; f1b=fp[fstr_]; f1c=fp[2*fstr_]; }
    bt = base+124; q0v=*(const float4*)(Qg+bt*256+qoff); p0v=pg[bt*16+j]; c0v=cug[bt*4+q4];
    { const float* fp = fBase + bt*fMul + fOfs; f0a=fp[0]; f0b=fp[fstr_]; f0c=fp[2*fstr_]; }
  }
  FT1[wix] = f3a; FT1[wix+1] = f3b; FT1[wix+2] = f3c;

  // ---- backward scan, unrolled x4 with slot rotation ----
  #pragma unroll 1
  for (int tb = TT-1; tb >= 3; tb -= 4) {
    BW_BODY(tb,   q3v, p3v, c3v,  f2a,f2b,f2c,  f3a,f3b,f3c, FT1, FT0)
    BW_BODY(tb-1, q2v, p2v, c2v,  f1a,f1b,f1c,  f2a,f2b,f2c, FT0, FT1)
    BW_BODY(tb-2, q1v, p1v, c1v,  f0a,f0b,f0c,  f1a,f1b,f1c, FT1, FT0)
    BW_BODY(tb-3, q0v, p0v, c0v,  f3a,f3b,f3c,  f0a,f0b,f0c, FT0, FT1)
  }

  // ---- coalesced us flush (replaces per-body predicated global store) ----
  #pragma unroll
  for (int i_ = 0; i_ < 8; ++i_) us_out[b*512 + i_*64 + l] = uL[i_*64 + l];

  // ---------------- forward rollout + cost ----------------
  const int i4  = l >> 2;
  const int c0f = q4 << 2;
  const int i4c = (i4 < 12) ? i4 : 11;
  const int sl0 = (c0f+0)<<2, sl1 = (c0f+1)<<2, sl2 = (c0f+2)<<2, sl3 = (c0f+3)<<2;
  float s = xinit[b*12 + i4c];
  float cacc = 0.f;

  // de-predicated x store + cost mask
  const bool xc_ = (q4 == 0) && (i4 < 12);
  float* xpt = xc_ ? (xsL + i4) : (dmpS + l);
  const int xstp = xc_ ? 12 : 0;
  const float q0m = (q4 == 0) ? 1.0f : 0.0f;

  const long bt0 = base;
  float4 qfA = *(const float4*)(Qg + bt0*256 + 4*l);
  float4 ffA = (q4 < 3) ? *(const float4*)(Ag + bt0*144 + i4c*12 + c0f)
                        : *(const float4*)(Bg + bt0*48  + i4c*4);
  float  pfA = pg[bt0*16 + i4];
  float4 qfB = *(const float4*)(Qg + (bt0+1)*256 + 4*l);
  float4 ffB = (q4 < 3) ? *(const float4*)(Ag + (bt0+1)*144 + i4c*12 + c0f)
                        : *(const float4*)(Bg + (bt0+1)*48  + i4c*4);
  float  pfB = pg[(bt0+1)*16 + i4];
  float4 qfC = *(const float4*)(Qg + (bt0+2)*256 + 4*l);
  float4 ffC = (q4 < 3) ? *(const float4*)(Ag + (bt0+2)*144 + i4c*12 + c0f)
                        : *(const float4*)(Bg + (bt0+2)*48  + i4c*4);
  float  pfC = pg[(bt0+2)*16 + i4];

  #pragma unroll 1
  for (int t = 0; t < TT; ++t) {
    const long btp = bt0 + ((t+3 < TT-1) ? t+3 : TT-1);
    float4 qfD = *(const float4*)(Qg + btp*256 + 4*l);
    float4 ffD = (q4 < 3) ? *(const float4*)(Ag + btp*144 + i4c*12 + c0f)
                          : *(const float4*)(Bg + btp*48  + i4c*4);
    float  pfD = pg[btp*16 + i4];

    float4 u4 = *(const float4*)(uL + t*4);

    float4 xg;
    xg.x = __shfl(s, sl0, 64); xg.y = __shfl(s, sl1, 64);
    xg.z = __shfl(s, sl2, 64); xg.w = __shfl(s, sl3, 64);
    float4 xuq = (q4 < 3) ? xg : u4;
    float xui = (i4 < 12) ? s
              : (i4 == 12) ? u4.x : (i4 == 13) ? u4.y : (i4 == 14) ? u4.z : u4.w;

    xpt[0] = s; xpt += xstp;

    cacc += 0.5f * xui * dotf4(qfA, xuq);
    cacc += q0m * (xui * pfA);

    float zx = dotf4(ffA, xuq);
    zx += dpp_qx1(zx);
    zx += dpp_qx2(zx);
    s = zx;

    qfA = qfB; ffA = ffB; pfA = pfB;
    qfB = qfC; ffB = ffC; pfB = pfC;
    qfC = qfD; ffC = ffD; pfC = pfD;
  }

  // ---- coalesced xs flush ----
  #pragma unroll
  for (int i_ = 0; i_ < 24; ++i_) xs_out[b*1536 + i_*64 + l] = xsL[i_*64 + l];

  cacc += __shfl_xor(cacc, 32, 64);
  cacc += __shfl_xor(cacc, 16, 64);
  cacc += __shfl_xor(cacc, 8, 64);
  cacc += __shfl_xor(cacc, 4, 64);
  cacc += dpp_qx2(cacc);
  cacc += dpp_qx1(cacc);
  if (l == 0) c_out[b] = cacc;
}

extern "C" void kernel_launch(void* const* d_in, const int* in_sizes, int n_in,
                              void* d_out, int out_size, void* d_ws, size_t ws_size,
                              hipStream_t stream) {
  const float* xinit = (const float*)d_in[0];
  // d_in[1] = current_x (unused by reference), d_in[7] = time (unused)
  const float* cu = (const float*)d_in[2];
  const float* Q  = (const float*)d_in[3];
  const float* p  = (const float*)d_in[4];
  const float* A  = (const float*)d_in[5];
  const float* Bm = (const float*)d_in[6];
  float* out = (float*)d_out;

  lqr_fused<<<dim3(NBQ), dim3(64), 0, stream>>>(Q, p, A, Bm, cu, xinit, out);
}